// Round 15
// baseline (533.887 us; speedup 1.0000x reference)
//
#include <hip/hip_runtime.h>
#include <math.h>

// ---------------------------------------------------------------------------
// PiT: encoder lift -> down pos-att -> 4x (pos-att + MLP + residual) -> up
// pos-att -> decoder. Sparse attention: wave-per-row single-pass sampled
// window filter (ballot-compacted, atomic-free) + value-space bisection for
// exact percentile order stats, fused softmax+PV. Dense linears: split-bf16
// MFMA; mlp2+res fused dual-GEMM.
// ---------------------------------------------------------------------------

typedef short bf16x8 __attribute__((ext_vector_type(8)));
typedef float f32x4 __attribute__((ext_vector_type(4)));

__device__ __forceinline__ float gelu_f(float x) {
  float x3 = x * x * x;
  float inner = x + 0.044715f * x3;
  float t = tanhf(0.7978845608028654f * inner);
  return x * (0.5f * (1.0f + t));
}

__device__ __forceinline__ unsigned short f2bf(float x) {
  union { float f; unsigned u; } v; v.f = x;
  return (unsigned short)((v.u + 0x7fffu + ((v.u >> 16) & 1u)) >> 16);
}
__device__ __forceinline__ float bf2f(unsigned short b) {
  union { unsigned u; float f; } v; v.u = ((unsigned)b) << 16; return v.f;
}
__device__ __forceinline__ void store_bf(unsigned short* hi, unsigned short* lo,
                                         size_t i, float v) {
  unsigned short h = f2bf(v);
  hi[i] = h;
  lo[i] = f2bf(v - bf2f(h));
}

// ------- weight prep: f32 -> bf16 hi/lo (+ val transpose) + scales ----------
struct PrepArgs {
  const float *mlp1, *mlp2, *res, *de1, *down, *pa, *up;
  const float *down_r, *pa_r, *up_r;
  unsigned short *rm_hi, *rm_lo, *val_hi, *val_lo;
  float* scales;
};
__global__ __launch_bounds__(256) void k_prep(PrepArgs p) {
  if (blockIdx.x == 4864) {
    int t = threadIdx.x;
    if (t >= 48) return;
    float rv;
    if (t < 8) rv = p.down_r[t];
    else if (t < 40) rv = p.pa_r[t - 8];
    else rv = p.up_r[t - 40];
    double rd = (double)rv;
    float s1 = (float)sin(rd);
    float u = 1.0f + s1;
    float vc = (float)(0.7853981633974483 * (1.0 - 1e-7));
    float wf = vc * u;
    p.scales[t] = (float)tan((double)wf);
    return;
  }
  int i = blockIdx.x * 256 + threadIdx.x;
  if (i < 851968) {
    const float* src; int off;
    if (i < 262144)      { src = p.mlp1; off = i; }
    else if (i < 524288) { src = p.mlp2; off = i - 262144; }
    else if (i < 786432) { src = p.res;  off = i - 524288; }
    else                 { src = p.de1;  off = i - 786432; }
    float x = src[off];
    store_bf(p.rm_hi, p.rm_lo, i, x);
  } else if (i < 1245184) {
    int ii = i - 851968;
    const float* src; int off;
    if (ii < 65536)       { src = p.down; off = ii; }
    else if (ii < 327680) { src = p.pa;   off = ii - 65536; }
    else                  { src = p.up;   off = ii - 327680; }
    int m = off >> 16, rem = off & 65535;
    int o = rem >> 8, j = rem & 255;  // dst row-major [o][j]
    float x = src[(size_t)m * 65536 + (o >> 5) * 8192 + j * 32 + (o & 31)];
    store_bf(p.val_hi, p.val_lo, ii, x);
  }
}

// ---------------- encoder lift: bf16 hi/lo output ---------------------------
__global__ __launch_bounds__(256) void k_lift(const float* __restrict__ x,
                                              const float* __restrict__ w,
                                              const float* __restrict__ b,
                                              unsigned short* __restrict__ ohi,
                                              unsigned short* __restrict__ olo) {
  int gid = blockIdx.x * 256 + threadIdx.x;
  int m = gid >> 8, o = gid & 255;
  float a0 = x[m * 3 + 0], a1 = x[m * 3 + 1], a2 = x[m * 3 + 2];
  float acc = a0 * w[o * 3 + 0] + a1 * w[o * 3 + 1] + a2 * w[o * 3 + 2] + b[o];
  store_bf(ohi, olo, gid, gelu_f(acc));
}

// ---------------- split-bf16 MFMA GEMM: C = act(A @ W'^T + bias [+ D]) ------
template <int ACT, int ADDRES, int OBF16>
__global__ __launch_bounds__(256) void k_gemm(
    const unsigned short* __restrict__ Ahi, const unsigned short* __restrict__ Alo,
    const unsigned short* __restrict__ Whi, const unsigned short* __restrict__ Wlo,
    const float* __restrict__ bias, const float* __restrict__ D,
    float* __restrict__ C, unsigned short* __restrict__ Chi,
    unsigned short* __restrict__ Clo) {
  int t = threadIdx.x;
  int w = t >> 6, l = t & 63;
  int m0 = blockIdx.x * 64 + (w >> 1) * 32;
  int o0 = blockIdx.y * 64 + (w & 1) * 32;
  int fr = l & 15, fq = l >> 4;
  f32x4 acc[2][2] = {};
  size_t a0 = (size_t)(m0 + fr) * 256 + fq * 8;
  size_t a1 = a0 + 16 * 256;
  size_t b0 = (size_t)(o0 + fr) * 256 + fq * 8;
  size_t b1 = b0 + 16 * 256;
#define MFMA4(ACC, AH, AL, BH, BL)                                            \
  ACC = __builtin_amdgcn_mfma_f32_16x16x32_bf16(AH, BH, ACC, 0, 0, 0);        \
  ACC = __builtin_amdgcn_mfma_f32_16x16x32_bf16(AH, BL, ACC, 0, 0, 0);        \
  ACC = __builtin_amdgcn_mfma_f32_16x16x32_bf16(AL, BH, ACC, 0, 0, 0);        \
  ACC = __builtin_amdgcn_mfma_f32_16x16x32_bf16(AL, BL, ACC, 0, 0, 0);
  for (int ks = 0; ks < 8; ++ks) {
    int k0 = ks * 32;
    bf16x8 A0h = *(const bf16x8*)(Ahi + a0 + k0);
    bf16x8 A0l = *(const bf16x8*)(Alo + a0 + k0);
    bf16x8 A1h = *(const bf16x8*)(Ahi + a1 + k0);
    bf16x8 A1l = *(const bf16x8*)(Alo + a1 + k0);
    bf16x8 B0h = *(const bf16x8*)(Whi + b0 + k0);
    bf16x8 B0l = *(const bf16x8*)(Wlo + b0 + k0);
    bf16x8 B1h = *(const bf16x8*)(Whi + b1 + k0);
    bf16x8 B1l = *(const bf16x8*)(Wlo + b1 + k0);
    MFMA4(acc[0][0], A0h, A0l, B0h, B0l)
    MFMA4(acc[0][1], A0h, A0l, B1h, B1l)
    MFMA4(acc[1][0], A1h, A1l, B0h, B0l)
    MFMA4(acc[1][1], A1h, A1l, B1h, B1l)
  }
  float bb[2];
  bb[0] = bias ? bias[o0 + fr] : 0.0f;
  bb[1] = bias ? bias[o0 + 16 + fr] : 0.0f;
#pragma unroll
  for (int i = 0; i < 2; ++i) {
#pragma unroll
    for (int jx = 0; jx < 2; ++jx) {
      int col = o0 + jx * 16 + fr;
#pragma unroll
      for (int r = 0; r < 4; ++r) {
        int rowi = m0 + i * 16 + fq * 4 + r;
        size_t oidx = (size_t)rowi * 256 + col;
        float v = acc[i][jx][r] + bb[jx];
        if (ADDRES) v += D[oidx];
        if (ACT) v = gelu_f(v);
        if (OBF16) store_bf(Chi, Clo, oidx, v);
        else C[oidx] = v;
      }
    }
  }
}

// ------- dual GEMM: C = gelu(A1@W1'^T + A2@W2'^T + b1 + b2), bf16 out -------
__global__ __launch_bounds__(256) void k_gemm2(
    const unsigned short* __restrict__ A1hi, const unsigned short* __restrict__ A1lo,
    const unsigned short* __restrict__ W1hi, const unsigned short* __restrict__ W1lo,
    const unsigned short* __restrict__ A2hi, const unsigned short* __restrict__ A2lo,
    const unsigned short* __restrict__ W2hi, const unsigned short* __restrict__ W2lo,
    const float* __restrict__ b1, const float* __restrict__ b2,
    unsigned short* __restrict__ Chi, unsigned short* __restrict__ Clo) {
  int t = threadIdx.x;
  int w = t >> 6, l = t & 63;
  int m0 = blockIdx.x * 64 + (w >> 1) * 32;
  int o0 = blockIdx.y * 64 + (w & 1) * 32;
  int fr = l & 15, fq = l >> 4;
  f32x4 acc[2][2] = {};
  size_t a0 = (size_t)(m0 + fr) * 256 + fq * 8;
  size_t a1 = a0 + 16 * 256;
  size_t b0 = (size_t)(o0 + fr) * 256 + fq * 8;
  size_t b1o = b0 + 16 * 256;
  for (int ks = 0; ks < 8; ++ks) {
    int k0 = ks * 32;
    {
      bf16x8 A0h = *(const bf16x8*)(A1hi + a0 + k0);
      bf16x8 A0l = *(const bf16x8*)(A1lo + a0 + k0);
      bf16x8 A1h_ = *(const bf16x8*)(A1hi + a1 + k0);
      bf16x8 A1l_ = *(const bf16x8*)(A1lo + a1 + k0);
      bf16x8 B0h = *(const bf16x8*)(W1hi + b0 + k0);
      bf16x8 B0l = *(const bf16x8*)(W1lo + b0 + k0);
      bf16x8 B1h = *(const bf16x8*)(W1hi + b1o + k0);
      bf16x8 B1l = *(const bf16x8*)(W1lo + b1o + k0);
      MFMA4(acc[0][0], A0h, A0l, B0h, B0l)
      MFMA4(acc[0][1], A0h, A0l, B1h, B1l)
      MFMA4(acc[1][0], A1h_, A1l_, B0h, B0l)
      MFMA4(acc[1][1], A1h_, A1l_, B1h, B1l)
    }
    {
      bf16x8 A0h = *(const bf16x8*)(A2hi + a0 + k0);
      bf16x8 A0l = *(const bf16x8*)(A2lo + a0 + k0);
      bf16x8 A1h_ = *(const bf16x8*)(A2hi + a1 + k0);
      bf16x8 A1l_ = *(const bf16x8*)(A2lo + a1 + k0);
      bf16x8 B0h = *(const bf16x8*)(W2hi + b0 + k0);
      bf16x8 B0l = *(const bf16x8*)(W2lo + b0 + k0);
      bf16x8 B1h = *(const bf16x8*)(W2hi + b1o + k0);
      bf16x8 B1l = *(const bf16x8*)(W2lo + b1o + k0);
      MFMA4(acc[0][0], A0h, A0l, B0h, B0l)
      MFMA4(acc[0][1], A0h, A0l, B1h, B1l)
      MFMA4(acc[1][0], A1h_, A1l_, B0h, B0l)
      MFMA4(acc[1][1], A1h_, A1l_, B1h, B1l)
    }
  }
#undef MFMA4
  float bb[2];
  bb[0] = b1[o0 + fr] + b2[o0 + fr];
  bb[1] = b1[o0 + 16 + fr] + b2[o0 + 16 + fr];
#pragma unroll
  for (int i = 0; i < 2; ++i) {
#pragma unroll
    for (int jx = 0; jx < 2; ++jx) {
      int col = o0 + jx * 16 + fr;
#pragma unroll
      for (int r = 0; r < 4; ++r) {
        int rowi = m0 + i * 16 + fq * 4 + r;
        size_t oidx = (size_t)rowi * 256 + col;
        store_bf(Chi, Clo, oidx, gelu_f(acc[i][jx][r] + bb[jx]));
      }
    }
  }
}

// ---------------- wave-per-row fused select + softmax + PV (one-pass) -------
// One 64-lane wave per (h, q-row); no __syncthreads, NO LDS atomics: the
// window filter compacts candidates via ballot/popcount prefix (deterministic
// index order). Sample 256 elems -> window estimate; ONE fused pass computes
// exact min/max AND pushes candidates. Exact order stats via value-space
// bisection; guards force an L2-hot refilter on any sampling miss -> exact on
// any data. Threshold on f32-rounded products = reference-exact semantics.
template <int N, int CAP, int MW>
__global__ __launch_bounds__(256, MW) void k_wselpv(
    const float* __restrict__ mdist, const float* __restrict__ scales,
    int sc_off, int Nq, int k_lo, float hw, float lw, float frac,
    const float* __restrict__ V, int Nk,
    unsigned short* __restrict__ out_hi, unsigned short* __restrict__ out_lo) {
  constexpr int CH = N / 256;
  constexpr int SMAX = (CAP + 63) / 64;
  __shared__ float cv[4][CAP];
  __shared__ int ci[4][CAP];
  __shared__ float svsel[4][2];
  __shared__ float swin[4][32];

  int tid = threadIdx.x;
  int w = tid >> 6, l = tid & 63;
  int row = blockIdx.x * 4 + w;
  int h = row / Nq, j = row - h * Nq;
  float scale = scales[sc_off + h];
  const float4* mrow4 = (const float4*)(mdist + (size_t)row * N);
  unsigned long long mlt = (l == 0) ? 0ull : (~0ull >> (64 - l));

  // ---- sample first 256 elems -> window estimate ----
  float4 s0 = mrow4[l];
  float smin = fminf(fminf(s0.x, s0.y), fminf(s0.z, s0.w));
  float smax = fmaxf(fmaxf(s0.x, s0.y), fmaxf(s0.z, s0.w));
#pragma unroll
  for (int off = 32; off > 0; off >>= 1) {
    smin = fminf(smin, __shfl_xor(smin, off));
    smax = fmaxf(smax, __shfl_xor(smax, off));
  }
  float est = smin + (smax - smin) * frac;

// ballot-compacted candidate push: deterministic, no atomics
#define PUSH(COND, VAL, IDX)                                                  \
  {                                                                           \
    bool hit_ = (COND);                                                       \
    unsigned long long bal_ = __ballot(hit_);                                 \
    int p_ = cnt + (int)__popcll(bal_ & mlt);                                 \
    if (hit_ && p_ < CAP) { cv[w][p_] = (VAL); ci[w][p_] = (IDX); }           \
    cnt += (int)__popcll(bal_);                                               \
  }

  // ---- fused single pass: exact min/max + candidate push (v < est) ----
  int cnt = 0;
  float lmin = INFINITY, lmax = -INFINITY;
#pragma unroll 4
  for (int e = 0; e < CH; ++e) {
    float4 v = mrow4[l + 64 * e];
    lmin = fminf(lmin, fminf(fminf(v.x, v.y), fminf(v.z, v.w)));
    lmax = fmaxf(lmax, fmaxf(fmaxf(v.x, v.y), fmaxf(v.z, v.w)));
    int i0 = 4 * (l + 64 * e);
    PUSH(v.x < est, v.x, i0)
    PUSH(v.y < est, v.y, i0 + 1)
    PUSH(v.z < est, v.z, i0 + 2)
    PUSH(v.w < est, v.w, i0 + 3)
  }
#pragma unroll
  for (int off = 32; off > 0; off >>= 1) {
    lmin = fminf(lmin, __shfl_xor(lmin, off));
    lmax = fmaxf(lmax, __shfl_xor(lmax, off));
  }
  float rmin = lmin, rmax = lmax;

  int K = 0;
  float inv_total = 1.0f;
  if (rmax > rmin) {
    float range = rmax - rmin;
    float margin = fmaxf(fabsf(rmax) * 1e-6f, 1e-30f);
    float rtop = rmax + margin;
    float wtop = est;
    bool have = true;
    if (!(wtop > rmin)) {
      wtop = rmin + range * frac;
      if (!(wtop > rmin)) wtop = rtop;
      have = false;
    }
    int attempt = 0;
    float v_lo = rmin, v_hi = rmin;
    int count = cnt;
    float xv[SMAX];
    for (int it = 0; it < 20; ++it) {
      if (!have) {
        cnt = 0;
#pragma unroll 4
        for (int e = 0; e < CH; ++e) {
          float4 v = mrow4[l + 64 * e];
          int i0 = 4 * (l + 64 * e);
          PUSH(v.x < wtop, v.x, i0)
          PUSH(v.y < wtop, v.y, i0 + 1)
          PUSH(v.z < wtop, v.z, i0 + 2)
          PUSH(v.w < wtop, v.w, i0 + 3)
        }
        have = true;
        count = cnt;
      }
      if (count < k_lo + 2) {
        wtop = (attempt == 0) ? (rmin + range * frac)
                              : fminf(rmin + (wtop - rmin) * 3.0f, rtop);
        if (!(wtop > rmin)) wtop = rtop;
        attempt++; have = false; continue;
      }
      if (count > CAP) {
        float fw = rmin + range * frac;
        float sw = rmin + (wtop - rmin) * 0.6f;
        wtop = (attempt == 0) ? fminf(fw, sw) : sw;
        attempt++; have = false; continue;
      }

      // candidates into regs
#pragma unroll
      for (int s = 0; s < SMAX; ++s) {
        int slot = l + 64 * s;
        xv[s] = (slot < count) ? cv[w][slot] : INFINITY;
      }
      // ---- value-space bisection; window always holds ranks k_lo, k_lo+1 ---
      float wlo = rmin, whi = wtop;
      int rbase = 0, cntw = count;
      int found = 0, degen = 0;
      for (int bs = 0; bs < 32; ++bs) {
        if (cntw <= 24) break;
        float mid = 0.5f * (wlo + whi);
        if (!(mid > wlo && mid < whi)) { degen = 1; break; }
        int c4 = 0;
#pragma unroll
        for (int s = 0; s < SMAX; ++s) c4 += (xv[s] >= wlo && xv[s] < mid) ? 1 : 0;
#pragma unroll
        for (int off = 32; off > 0; off >>= 1) c4 += __shfl_xor(c4, off);
        int rrel = k_lo - rbase;
        if (rrel + 1 < c4) { whi = mid; cntw = c4; }
        else if (rrel >= c4) { wlo = mid; rbase += c4; cntw -= c4; }
        else {
          float mx = -INFINITY, mn = INFINITY;
#pragma unroll
          for (int s = 0; s < SMAX; ++s) {
            float v = xv[s];
            if (v >= wlo && v < mid) mx = fmaxf(mx, v);
            if (v >= mid && v < whi) mn = fminf(mn, v);
          }
#pragma unroll
          for (int off = 32; off > 0; off >>= 1) {
            mx = fmaxf(mx, __shfl_xor(mx, off));
            mn = fminf(mn, __shfl_xor(mn, off));
          }
          v_lo = mx; v_hi = mn; found = 1;
          break;
        }
      }
      if (!found) {
        if (!degen && cntw <= 32) {
          // ballot-gather in-window candidates into tiny list
          int gb = 0;
#pragma unroll
          for (int s = 0; s < SMAX; ++s) {
            float v = xv[s];
            bool in = (v >= wlo && v < whi);
            unsigned long long bal = __ballot(in);
            int p = gb + (int)__popcll(bal & mlt);
            if (in && p < 32) swin[w][p] = v;
            gb += (int)__popcll(bal);
          }
          int m = gb;
          if (m > 32) m = 32;
          float myv = (l < m) ? swin[w][l] : INFINITY;
          int clt = 0, ceq = 0;
          for (int jj = 0; jj < m; ++jj) {
            float y = swin[w][jj];
            clt += (y < myv) ? 1 : 0;
            ceq += (y == myv) ? 1 : 0;
          }
          int rr = k_lo - rbase;
          if (l < m) {
            if (clt <= rr && rr < clt + ceq) svsel[w][0] = myv;
            if (clt <= rr + 1 && rr + 1 < clt + ceq) svsel[w][1] = myv;
          }
          v_lo = svsel[w][0];
          v_hi = svsel[w][1];
        } else {
          int clt[SMAX], ceq[SMAX];
#pragma unroll
          for (int s = 0; s < SMAX; ++s) { clt[s] = 0; ceq[s] = 0; }
          for (int jj = 0; jj < count; ++jj) {
            float y = cv[w][jj];
#pragma unroll
            for (int s = 0; s < SMAX; ++s) {
              clt[s] += (y < xv[s]) ? 1 : 0;
              ceq[s] += (y == xv[s]) ? 1 : 0;
            }
          }
#pragma unroll
          for (int s = 0; s < SMAX; ++s) {
            int slot = l + 64 * s;
            if (slot < count) {
              if (clt[s] <= k_lo && k_lo < clt[s] + ceq[s]) svsel[w][0] = xv[s];
              if (clt[s] <= k_lo + 1 && k_lo + 1 < clt[s] + ceq[s]) svsel[w][1] = xv[s];
            }
          }
          v_lo = svsel[w][0];
          v_hi = svsel[w][1];
        }
      }
      // guard: every non-candidate (>= wtop) must be excluded by thr
      float vlos0 = __fmul_rn(v_lo, scale);
      float vhis0 = __fmul_rn(v_hi, scale);
      float thr0 = __fadd_rn(__fmul_rn(vlos0, lw), __fmul_rn(vhis0, hw));
      if (__fmul_rn(wtop, scale) <= thr0) {
        wtop = fminf(rmin + (wtop - rmin) * 3.0f, rtop);
        attempt++; have = false; continue;
      }
      break;
    }
#undef PUSH

    float vlos = __fmul_rn(v_lo, scale);
    float vhis = __fmul_rn(v_hi, scale);
    float thr = __fadd_rn(__fmul_rn(vlos, lw), __fmul_rn(vhis, hw));
    float rmins = __fmul_rn(rmin, scale);

    int oi[SMAX]; int kp[SMAX];
#pragma unroll
    for (int s = 0; s < SMAX; ++s) {
      int slot = l + 64 * s;
      oi[s] = 0; kp[s] = 0;
      if (slot < count) {
        oi[s] = ci[w][slot];
        kp[s] = (__fmul_rn(xv[s], scale) <= thr) ? 1 : 0;
      }
    }
    int base = 0;
    float lsum = 0.0f;
#pragma unroll
    for (int s = 0; s < SMAX; ++s) {
      unsigned long long bal = __ballot(kp[s] != 0);
      int pos = base + (int)__popcll(bal & mlt);
      if (kp[s]) {
        float e0 = expf(__fsub_rn(rmins, __fmul_rn(xv[s], scale)));
        cv[w][pos] = e0;
        ci[w][pos] = oi[s];
        lsum += e0;
      }
      base += (int)__popcll(bal);
    }
    K = base;
#pragma unroll
    for (int off = 32; off > 0; off >>= 1) lsum += __shfl_xor(lsum, off);
    inv_total = 1.0f / lsum;
  } else {
    K = 0;
    inv_total = 1.0f / (float)Nk;
  }

  // ---- PV: lane = (batch b, col pair); one float2 load per element ----
  int b = l >> 4, c4 = (l & 15) * 2;
  int hcol = h * 32 + c4;
  const float* Vb = V + (size_t)b * Nk * 256;
  float acc0 = 0.0f, acc1 = 0.0f;
  if (K > 0) {
    for (int e = 0; e < K; ++e) {
      float we = cv[w][e];
      int n = ci[w][e];
      const float2 vv = *(const float2*)(Vb + (size_t)n * 256 + hcol);
      acc0 = fmaf(we, vv.x, acc0);
      acc1 = fmaf(we, vv.y, acc1);
    }
  } else {
    for (int n = 0; n < Nk; ++n) {
      const float2 vv = *(const float2*)(Vb + (size_t)n * 256 + hcol);
      acc0 += vv.x;
      acc1 += vv.y;
    }
  }
  size_t oidx = ((size_t)b * Nq + j) * 256 + hcol;
  store_bf(out_hi, out_lo, oidx, gelu_f(acc0 * inv_total));
  store_bf(out_hi, out_lo, oidx + 1, gelu_f(acc1 * inv_total));
}

// ---------------- final 256->1 projection -----------------------------------
__global__ __launch_bounds__(256) void k_de2(const float* __restrict__ A,
                                             const float* __restrict__ w,
                                             const float* __restrict__ b,
                                             float* __restrict__ out) {
  int t = threadIdx.x;
  int row = blockIdx.x * 4 + (t >> 6);
  int lane = t & 63;
  const float* ar = A + (size_t)row * 256;
  float s = 0.0f;
  for (int i = lane; i < 256; i += 64) s = fmaf(ar[i], w[i], s);
#pragma unroll
  for (int off = 32; off > 0; off >>= 1) s += __shfl_down(s, off);
  if (lane == 0) out[row] = s + b[0];
}

// ---------------------------------------------------------------------------
struct SelParams { int k_lo; float hw, lw, frac; };
static SelParams sel_params(double q, int N) {
  SelParams p;
  float idx_q = (float)(q / 100.0);
  float pos = idx_q * (float)(N - 1);
  float lo = floorf(pos);
  p.k_lo = (int)lo;
  p.hw = pos - lo;
  p.lw = 1.0f - p.hw;
  float need = (float)(p.k_lo + 2);
  p.frac = (need + 6.0f * sqrtf(need) + 8.0f) / (float)N;
  return p;
}

extern "C" void kernel_launch(void* const* d_in, const int* in_sizes, int n_in,
                              void* d_out, int out_size, void* d_ws, size_t ws_size,
                              hipStream_t stream) {
  const float* x      = (const float*)d_in[0];
  const float* mdd    = (const float*)d_in[1];
  const float* mdb    = (const float*)d_in[2];
  const float* mdu    = (const float*)d_in[3];
  const float* en_w   = (const float*)d_in[4];
  const float* en_b   = (const float*)d_in[5];
  const float* down_r = (const float*)d_in[6];
  const float* down_w = (const float*)d_in[7];
  const float* pa_r   = (const float*)d_in[8];
  const float* pa_w   = (const float*)d_in[9];
  const float* mlp1_w = (const float*)d_in[10];
  const float* mlp1_b = (const float*)d_in[11];
  const float* mlp2_w = (const float*)d_in[12];
  const float* mlp2_b = (const float*)d_in[13];
  const float* res_w  = (const float*)d_in[14];
  const float* res_b  = (const float*)d_in[15];
  const float* up_r   = (const float*)d_in[16];
  const float* up_w   = (const float*)d_in[17];
  const float* de1_w  = (const float*)d_in[18];
  const float* de1_b  = (const float*)d_in[19];
  const float* de2_w  = (const float*)d_in[20];
  const float* de2_b  = (const float*)d_in[21];
  float* out = (float*)d_out;
  char* base = (char*)d_ws;

  float* val               = (float*)base;                        // 16.78 MB (also de1 out)
  unsigned short* hB_hi    = (unsigned short*)(base + 16777216);  // 2.10 MB
  unsigned short* hB_lo    = (unsigned short*)(base + 18874368);  // 2.10 MB
  unsigned short* hfull_hi = (unsigned short*)(base + 20971520);  // 8.39 MB
  unsigned short* hfull_lo = (unsigned short*)(base + 29360128);
  unsigned short* paout_hi = (unsigned short*)(base + 37748736);
  unsigned short* paout_lo = (unsigned short*)(base + 46137344);
  unsigned short* hA_hi    = (unsigned short*)(base + 54525952);  // 2.10 MB
  unsigned short* hA_lo    = (unsigned short*)(base + 56623104);
  unsigned short* t1_hi    = (unsigned short*)(base + 58720256);
  unsigned short* t1_lo    = (unsigned short*)(base + 60817408);
  unsigned short* wrm_hi   = (unsigned short*)(base + 62914560);  // 1.70 MB
  unsigned short* wrm_lo   = (unsigned short*)(base + 64618496);
  unsigned short* wval_hi  = (unsigned short*)(base + 66322432);  // 0.79 MB
  unsigned short* wval_lo  = (unsigned short*)(base + 67108864);
  float* scales            = (float*)(base + 67895296);

  PrepArgs pa;
  pa.mlp1 = mlp1_w; pa.mlp2 = mlp2_w; pa.res = res_w; pa.de1 = de1_w;
  pa.down = down_w; pa.pa = pa_w; pa.up = up_w;
  pa.down_r = down_r; pa.pa_r = pa_r; pa.up_r = up_r;
  pa.rm_hi = wrm_hi; pa.rm_lo = wrm_lo; pa.val_hi = wval_hi; pa.val_lo = wval_lo;
  pa.scales = scales;
  k_prep<<<4865, 256, 0, stream>>>(pa);

  // encoder
  k_lift<<<16384, 256, 0, stream>>>(x, en_w, en_b, hfull_hi, hfull_lo);

  // down stage (H=8, Nq=1024, Nk=4096, q=3 -> keep ~124)
  SelParams pd = sel_params(3.0, 4096);
  k_gemm<0, 0, 0><<<dim3(256, 4), 256, 0, stream>>>(
      hfull_hi, hfull_lo, wval_hi, wval_lo, nullptr, nullptr, val, nullptr, nullptr);
  k_wselpv<4096, 256, 4><<<2048, 256, 0, stream>>>(
      mdd, scales, 0, 1024, pd.k_lo, pd.hw, pd.lw, pd.frac, val, 4096, hA_hi, hA_lo);

  // processor blocks (Nq=Nk=1024, q=5 -> keep ~53); hlat ping-pongs A<->B
  SelParams pb = sel_params(5.0, 1024);
  for (int i = 0; i < 4; i++) {
    unsigned short* in_hi  = (i & 1) ? hB_hi : hA_hi;
    unsigned short* in_lo  = (i & 1) ? hB_lo : hA_lo;
    unsigned short* out_hi = (i & 1) ? hA_hi : hB_hi;
    unsigned short* out_lo = (i & 1) ? hA_lo : hB_lo;
    k_gemm<0, 0, 0><<<dim3(64, 4), 256, 0, stream>>>(
        in_hi, in_lo, wval_hi + 65536 + i * 65536, wval_lo + 65536 + i * 65536,
        nullptr, nullptr, val, nullptr, nullptr);
    k_wselpv<1024, 256, 8><<<2048, 256, 0, stream>>>(
        mdb + (size_t)i * 8388608, scales, 8 + i * 8, 1024, pb.k_lo, pb.hw, pb.lw,
        pb.frac, val, 1024, paout_hi, paout_lo);
    k_gemm<1, 0, 1><<<dim3(64, 4), 256, 0, stream>>>(
        paout_hi, paout_lo, wrm_hi + i * 65536, wrm_lo + i * 65536,
        mlp1_b + i * 256, nullptr, nullptr, t1_hi, t1_lo);
    k_gemm2<<<dim3(64, 4), 256, 0, stream>>>(
        t1_hi, t1_lo, wrm_hi + 262144 + i * 65536, wrm_lo + 262144 + i * 65536,
        in_hi, in_lo, wrm_hi + 524288 + i * 65536, wrm_lo + 524288 + i * 65536,
        mlp2_b + i * 256, res_b + i * 256, out_hi, out_lo);
  }
  // after 4 iterations the live hlat is back in hA

  // up stage (H=8, Nq=4096, Nk=1024, q=3 -> keep ~32)
  SelParams pu = sel_params(3.0, 1024);
  k_gemm<0, 0, 0><<<dim3(64, 4), 256, 0, stream>>>(
      hA_hi, hA_lo, wval_hi + 327680, wval_lo + 327680, nullptr, nullptr,
      val, nullptr, nullptr);
  k_wselpv<1024, 192, 8><<<8192, 256, 0, stream>>>(
      mdu, scales, 40, 4096, pu.k_lo, pu.hw, pu.lw, pu.frac, val, 1024,
      paout_hi, paout_lo);

  // decoder
  k_gemm<1, 0, 0><<<dim3(256, 4), 256, 0, stream>>>(
      paout_hi, paout_lo, wrm_hi + 786432, wrm_lo + 786432, de1_b, nullptr,
      val, nullptr, nullptr);
  k_de2<<<4096, 256, 0, stream>>>(val, de2_w, de2_b, out);
}

// Round 16
// 515.588 us; speedup vs baseline: 1.0355x; 1.0355x over previous
//
#include <hip/hip_runtime.h>
#include <math.h>

// ---------------------------------------------------------------------------
// PiT: encoder lift -> down pos-att -> 4x (pos-att + MLP + residual) -> up
// pos-att -> decoder. Sparse attention: wave-per-row SINGLE-PASS (sampled
// window, lean registers) filter + value-space bisection for exact percentile
// order stats, fused softmax+PV. Dense linears: split-bf16 MFMA; mlp2+res
// fused as a dual-GEMM. Lift fused into the prep kernel (independent work).
// ---------------------------------------------------------------------------

typedef short bf16x8 __attribute__((ext_vector_type(8)));
typedef float f32x4 __attribute__((ext_vector_type(4)));

__device__ __forceinline__ float gelu_f(float x) {
  float x3 = x * x * x;
  float inner = x + 0.044715f * x3;
  float t = tanhf(0.7978845608028654f * inner);
  return x * (0.5f * (1.0f + t));
}

__device__ __forceinline__ unsigned short f2bf(float x) {
  union { float f; unsigned u; } v; v.f = x;
  return (unsigned short)((v.u + 0x7fffu + ((v.u >> 16) & 1u)) >> 16);
}
__device__ __forceinline__ float bf2f(unsigned short b) {
  union { unsigned u; float f; } v; v.u = ((unsigned)b) << 16; return v.f;
}
__device__ __forceinline__ void store_bf(unsigned short* hi, unsigned short* lo,
                                         size_t i, float v) {
  unsigned short h = f2bf(v);
  hi[i] = h;
  lo[i] = f2bf(v - bf2f(h));
}

// -- weight prep: f32 -> bf16 hi/lo (+ val transpose) + scales + lift --------
struct PrepArgs {
  const float *mlp1, *mlp2, *res, *de1, *down, *pa, *up;
  const float *down_r, *pa_r, *up_r;
  const float *x, *en_w, *en_b;
  unsigned short *rm_hi, *rm_lo, *val_hi, *val_lo;
  unsigned short *hfull_hi, *hfull_lo;
  float* scales;
};
__global__ __launch_bounds__(256) void k_prep(PrepArgs p) {
  if (blockIdx.x >= 4865) {
    // encoder lift: out[m][o] = gelu(x[m].w[o] + b[o]), K=3
    int gid = (blockIdx.x - 4865) * 256 + threadIdx.x;
    int m = gid >> 8, o = gid & 255;
    float a0 = p.x[m * 3 + 0], a1 = p.x[m * 3 + 1], a2 = p.x[m * 3 + 2];
    float acc = a0 * p.en_w[o * 3 + 0] + a1 * p.en_w[o * 3 + 1] +
                a2 * p.en_w[o * 3 + 2] + p.en_b[o];
    store_bf(p.hfull_hi, p.hfull_lo, gid, gelu_f(acc));
    return;
  }
  if (blockIdx.x == 4864) {
    int t = threadIdx.x;
    if (t >= 48) return;
    float rv;
    if (t < 8) rv = p.down_r[t];
    else if (t < 40) rv = p.pa_r[t - 8];
    else rv = p.up_r[t - 40];
    double rd = (double)rv;
    float s1 = (float)sin(rd);
    float u = 1.0f + s1;
    float vc = (float)(0.7853981633974483 * (1.0 - 1e-7));
    float wf = vc * u;
    p.scales[t] = (float)tan((double)wf);
    return;
  }
  int i = blockIdx.x * 256 + threadIdx.x;
  if (i < 851968) {
    const float* src; int off;
    if (i < 262144)      { src = p.mlp1; off = i; }
    else if (i < 524288) { src = p.mlp2; off = i - 262144; }
    else if (i < 786432) { src = p.res;  off = i - 524288; }
    else                 { src = p.de1;  off = i - 786432; }
    float x = src[off];
    store_bf(p.rm_hi, p.rm_lo, i, x);
  } else if (i < 1245184) {
    int ii = i - 851968;
    const float* src; int off;
    if (ii < 65536)       { src = p.down; off = ii; }
    else if (ii < 327680) { src = p.pa;   off = ii - 65536; }
    else                  { src = p.up;   off = ii - 327680; }
    int m = off >> 16, rem = off & 65535;
    int o = rem >> 8, j = rem & 255;  // dst row-major [o][j]
    float x = src[(size_t)m * 65536 + (o >> 5) * 8192 + j * 32 + (o & 31)];
    store_bf(p.val_hi, p.val_lo, ii, x);
  }
}

// ---------------- split-bf16 MFMA GEMM: C = act(A @ W'^T + bias [+ D]) ------
template <int ACT, int ADDRES, int OBF16>
__global__ __launch_bounds__(256) void k_gemm(
    const unsigned short* __restrict__ Ahi, const unsigned short* __restrict__ Alo,
    const unsigned short* __restrict__ Whi, const unsigned short* __restrict__ Wlo,
    const float* __restrict__ bias, const float* __restrict__ D,
    float* __restrict__ C, unsigned short* __restrict__ Chi,
    unsigned short* __restrict__ Clo) {
  int t = threadIdx.x;
  int w = t >> 6, l = t & 63;
  int m0 = blockIdx.x * 64 + (w >> 1) * 32;
  int o0 = blockIdx.y * 64 + (w & 1) * 32;
  int fr = l & 15, fq = l >> 4;
  f32x4 acc[2][2] = {};
  size_t a0 = (size_t)(m0 + fr) * 256 + fq * 8;
  size_t a1 = a0 + 16 * 256;
  size_t b0 = (size_t)(o0 + fr) * 256 + fq * 8;
  size_t b1 = b0 + 16 * 256;
#define MFMA4(ACC, AH, AL, BH, BL)                                            \
  ACC = __builtin_amdgcn_mfma_f32_16x16x32_bf16(AH, BH, ACC, 0, 0, 0);        \
  ACC = __builtin_amdgcn_mfma_f32_16x16x32_bf16(AH, BL, ACC, 0, 0, 0);        \
  ACC = __builtin_amdgcn_mfma_f32_16x16x32_bf16(AL, BH, ACC, 0, 0, 0);        \
  ACC = __builtin_amdgcn_mfma_f32_16x16x32_bf16(AL, BL, ACC, 0, 0, 0);
  for (int ks = 0; ks < 8; ++ks) {
    int k0 = ks * 32;
    bf16x8 A0h = *(const bf16x8*)(Ahi + a0 + k0);
    bf16x8 A0l = *(const bf16x8*)(Alo + a0 + k0);
    bf16x8 A1h = *(const bf16x8*)(Ahi + a1 + k0);
    bf16x8 A1l = *(const bf16x8*)(Alo + a1 + k0);
    bf16x8 B0h = *(const bf16x8*)(Whi + b0 + k0);
    bf16x8 B0l = *(const bf16x8*)(Wlo + b0 + k0);
    bf16x8 B1h = *(const bf16x8*)(Whi + b1 + k0);
    bf16x8 B1l = *(const bf16x8*)(Wlo + b1 + k0);
    MFMA4(acc[0][0], A0h, A0l, B0h, B0l)
    MFMA4(acc[0][1], A0h, A0l, B1h, B1l)
    MFMA4(acc[1][0], A1h, A1l, B0h, B0l)
    MFMA4(acc[1][1], A1h, A1l, B1h, B1l)
  }
  float bb[2];
  bb[0] = bias ? bias[o0 + fr] : 0.0f;
  bb[1] = bias ? bias[o0 + 16 + fr] : 0.0f;
#pragma unroll
  for (int i = 0; i < 2; ++i) {
#pragma unroll
    for (int jx = 0; jx < 2; ++jx) {
      int col = o0 + jx * 16 + fr;
#pragma unroll
      for (int r = 0; r < 4; ++r) {
        int rowi = m0 + i * 16 + fq * 4 + r;
        size_t oidx = (size_t)rowi * 256 + col;
        float v = acc[i][jx][r] + bb[jx];
        if (ADDRES) v += D[oidx];
        if (ACT) v = gelu_f(v);
        if (OBF16) store_bf(Chi, Clo, oidx, v);
        else C[oidx] = v;
      }
    }
  }
}

// ------- dual GEMM: C = gelu(A1@W1'^T + A2@W2'^T + b1 + b2), bf16 out -------
__global__ __launch_bounds__(256) void k_gemm2(
    const unsigned short* __restrict__ A1hi, const unsigned short* __restrict__ A1lo,
    const unsigned short* __restrict__ W1hi, const unsigned short* __restrict__ W1lo,
    const unsigned short* __restrict__ A2hi, const unsigned short* __restrict__ A2lo,
    const unsigned short* __restrict__ W2hi, const unsigned short* __restrict__ W2lo,
    const float* __restrict__ b1, const float* __restrict__ b2,
    unsigned short* __restrict__ Chi, unsigned short* __restrict__ Clo) {
  int t = threadIdx.x;
  int w = t >> 6, l = t & 63;
  int m0 = blockIdx.x * 64 + (w >> 1) * 32;
  int o0 = blockIdx.y * 64 + (w & 1) * 32;
  int fr = l & 15, fq = l >> 4;
  f32x4 acc[2][2] = {};
  size_t a0 = (size_t)(m0 + fr) * 256 + fq * 8;
  size_t a1 = a0 + 16 * 256;
  size_t b0 = (size_t)(o0 + fr) * 256 + fq * 8;
  size_t b1o = b0 + 16 * 256;
  for (int ks = 0; ks < 8; ++ks) {
    int k0 = ks * 32;
    {
      bf16x8 A0h = *(const bf16x8*)(A1hi + a0 + k0);
      bf16x8 A0l = *(const bf16x8*)(A1lo + a0 + k0);
      bf16x8 A1h_ = *(const bf16x8*)(A1hi + a1 + k0);
      bf16x8 A1l_ = *(const bf16x8*)(A1lo + a1 + k0);
      bf16x8 B0h = *(const bf16x8*)(W1hi + b0 + k0);
      bf16x8 B0l = *(const bf16x8*)(W1lo + b0 + k0);
      bf16x8 B1h = *(const bf16x8*)(W1hi + b1o + k0);
      bf16x8 B1l = *(const bf16x8*)(W1lo + b1o + k0);
      MFMA4(acc[0][0], A0h, A0l, B0h, B0l)
      MFMA4(acc[0][1], A0h, A0l, B1h, B1l)
      MFMA4(acc[1][0], A1h_, A1l_, B0h, B0l)
      MFMA4(acc[1][1], A1h_, A1l_, B1h, B1l)
    }
    {
      bf16x8 A0h = *(const bf16x8*)(A2hi + a0 + k0);
      bf16x8 A0l = *(const bf16x8*)(A2lo + a0 + k0);
      bf16x8 A1h_ = *(const bf16x8*)(A2hi + a1 + k0);
      bf16x8 A1l_ = *(const bf16x8*)(A2lo + a1 + k0);
      bf16x8 B0h = *(const bf16x8*)(W2hi + b0 + k0);
      bf16x8 B0l = *(const bf16x8*)(W2lo + b0 + k0);
      bf16x8 B1h = *(const bf16x8*)(W2hi + b1o + k0);
      bf16x8 B1l = *(const bf16x8*)(W2lo + b1o + k0);
      MFMA4(acc[0][0], A0h, A0l, B0h, B0l)
      MFMA4(acc[0][1], A0h, A0l, B1h, B1l)
      MFMA4(acc[1][0], A1h_, A1l_, B0h, B0l)
      MFMA4(acc[1][1], A1h_, A1l_, B1h, B1l)
    }
  }
#undef MFMA4
  float bb[2];
  bb[0] = b1[o0 + fr] + b2[o0 + fr];
  bb[1] = b1[o0 + 16 + fr] + b2[o0 + 16 + fr];
#pragma unroll
  for (int i = 0; i < 2; ++i) {
#pragma unroll
    for (int jx = 0; jx < 2; ++jx) {
      int col = o0 + jx * 16 + fr;
#pragma unroll
      for (int r = 0; r < 4; ++r) {
        int rowi = m0 + i * 16 + fq * 4 + r;
        size_t oidx = (size_t)rowi * 256 + col;
        store_bf(Chi, Clo, oidx, gelu_f(acc[i][jx][r] + bb[jx]));
      }
    }
  }
}

// ---------------- wave-per-row fused select + softmax + PV (one-pass) -------
// One 64-lane wave per (h, q-row); no __syncthreads. Sample 256 elems ->
// window estimate; ONE fused pass (unroll-capped for lean VGPR) computes
// exact min/max AND pushes candidates. Exact order stats via value-space
// bisection; guards (count bounds, thr-guard) force L2-hot refilter with the
// exact-range frac ladder on any sampling miss -> exact on any data.
template <int N, int CAP, int MW>
__global__ __launch_bounds__(256, MW) void k_wselpv(
    const float* __restrict__ mdist, const float* __restrict__ scales,
    int sc_off, int Nq, int k_lo, float hw, float lw, float frac,
    const float* __restrict__ V, int Nk,
    unsigned short* __restrict__ out_hi, unsigned short* __restrict__ out_lo) {
  constexpr int CH = N / 256;
  constexpr int SMAX = (CAP + 63) / 64;
  __shared__ float cv[4][CAP];
  __shared__ int ci[4][CAP];
  __shared__ int ccnt[4];
  __shared__ float svsel[4][2];
  __shared__ float swin[4][32];

  int tid = threadIdx.x;
  int w = tid >> 6, l = tid & 63;
  int row = blockIdx.x * 4 + w;
  int h = row / Nq, j = row - h * Nq;
  float scale = scales[sc_off + h];
  const float4* mrow4 = (const float4*)(mdist + (size_t)row * N);

  // ---- sample first 256 elems -> window estimate ----
  float4 s0 = mrow4[l];
  float smin = fminf(fminf(s0.x, s0.y), fminf(s0.z, s0.w));
  float smax = fmaxf(fmaxf(s0.x, s0.y), fmaxf(s0.z, s0.w));
#pragma unroll
  for (int off = 32; off > 0; off >>= 1) {
    smin = fminf(smin, __shfl_xor(smin, off));
    smax = fmaxf(smax, __shfl_xor(smax, off));
  }
  float est = smin + (smax - smin) * frac;

  // ---- fused single pass: exact min/max + candidate push (v < est) ----
  if (l == 0) ccnt[w] = 0;
  float lmin = INFINITY, lmax = -INFINITY;
#pragma unroll 4
  for (int e = 0; e < CH; ++e) {
    float4 v = mrow4[l + 64 * e];
    lmin = fminf(lmin, fminf(fminf(v.x, v.y), fminf(v.z, v.w)));
    lmax = fmaxf(lmax, fmaxf(fmaxf(v.x, v.y), fmaxf(v.z, v.w)));
    int i0 = 4 * (l + 64 * e);
    if (v.x < est) { int p = atomicAdd(&ccnt[w], 1); if (p < CAP) { cv[w][p] = v.x; ci[w][p] = i0; } }
    if (v.y < est) { int p = atomicAdd(&ccnt[w], 1); if (p < CAP) { cv[w][p] = v.y; ci[w][p] = i0 + 1; } }
    if (v.z < est) { int p = atomicAdd(&ccnt[w], 1); if (p < CAP) { cv[w][p] = v.z; ci[w][p] = i0 + 2; } }
    if (v.w < est) { int p = atomicAdd(&ccnt[w], 1); if (p < CAP) { cv[w][p] = v.w; ci[w][p] = i0 + 3; } }
  }
#pragma unroll
  for (int off = 32; off > 0; off >>= 1) {
    lmin = fminf(lmin, __shfl_xor(lmin, off));
    lmax = fmaxf(lmax, __shfl_xor(lmax, off));
  }
  float rmin = lmin, rmax = lmax;

  int K = 0;
  float inv_total = 1.0f;
  if (rmax > rmin) {
    float range = rmax - rmin;
    float margin = fmaxf(fabsf(rmax) * 1e-6f, 1e-30f);
    float rtop = rmax + margin;
    float wtop = est;
    bool have = true;
    if (!(wtop > rmin)) {
      wtop = rmin + range * frac;
      if (!(wtop > rmin)) wtop = rtop;
      have = false;
    }
    int attempt = 0;
    float v_lo = rmin, v_hi = rmin;
    int count = 0;
    float xv[SMAX];
    for (int it = 0; it < 20; ++it) {
      if (!have) {
        if (l == 0) ccnt[w] = 0;
#pragma unroll 4
        for (int e = 0; e < CH; ++e) {
          float4 v = mrow4[l + 64 * e];
          int i0 = 4 * (l + 64 * e);
          if (v.x < wtop) { int p = atomicAdd(&ccnt[w], 1); if (p < CAP) { cv[w][p] = v.x; ci[w][p] = i0; } }
          if (v.y < wtop) { int p = atomicAdd(&ccnt[w], 1); if (p < CAP) { cv[w][p] = v.y; ci[w][p] = i0 + 1; } }
          if (v.z < wtop) { int p = atomicAdd(&ccnt[w], 1); if (p < CAP) { cv[w][p] = v.z; ci[w][p] = i0 + 2; } }
          if (v.w < wtop) { int p = atomicAdd(&ccnt[w], 1); if (p < CAP) { cv[w][p] = v.w; ci[w][p] = i0 + 3; } }
        }
        have = true;
      }
      count = ccnt[w];
      if (count < k_lo + 2) {
        wtop = (attempt == 0) ? (rmin + range * frac)
                              : fminf(rmin + (wtop - rmin) * 3.0f, rtop);
        if (!(wtop > rmin)) wtop = rtop;
        attempt++; have = false; continue;
      }
      if (count > CAP) {
        float fw = rmin + range * frac;
        float sw = rmin + (wtop - rmin) * 0.6f;
        wtop = (attempt == 0) ? fminf(fw, sw) : sw;
        attempt++; have = false; continue;
      }

      // candidates into regs
#pragma unroll
      for (int s = 0; s < SMAX; ++s) {
        int slot = l + 64 * s;
        xv[s] = (slot < count) ? cv[w][slot] : INFINITY;
      }
      // ---- value-space bisection; window always holds ranks k_lo, k_lo+1 ---
      float wlo = rmin, whi = wtop;
      int rbase = 0, cntw = count;
      int found = 0, degen = 0;
      for (int bs = 0; bs < 32; ++bs) {
        if (cntw <= 24) break;
        float mid = 0.5f * (wlo + whi);
        if (!(mid > wlo && mid < whi)) { degen = 1; break; }
        int c4 = 0;
#pragma unroll
        for (int s = 0; s < SMAX; ++s) c4 += (xv[s] >= wlo && xv[s] < mid) ? 1 : 0;
#pragma unroll
        for (int off = 32; off > 0; off >>= 1) c4 += __shfl_xor(c4, off);
        int rrel = k_lo - rbase;
        if (rrel + 1 < c4) { whi = mid; cntw = c4; }
        else if (rrel >= c4) { wlo = mid; rbase += c4; cntw -= c4; }
        else {
          float mx = -INFINITY, mn = INFINITY;
#pragma unroll
          for (int s = 0; s < SMAX; ++s) {
            float v = xv[s];
            if (v >= wlo && v < mid) mx = fmaxf(mx, v);
            if (v >= mid && v < whi) mn = fminf(mn, v);
          }
#pragma unroll
          for (int off = 32; off > 0; off >>= 1) {
            mx = fmaxf(mx, __shfl_xor(mx, off));
            mn = fminf(mn, __shfl_xor(mn, off));
          }
          v_lo = mx; v_hi = mn; found = 1;
          break;
        }
      }
      if (!found) {
        if (!degen && cntw <= 32) {
          if (l == 0) ccnt[w] = 0;
#pragma unroll
          for (int s = 0; s < SMAX; ++s) {
            float v = xv[s];
            if (v >= wlo && v < whi) {
              int p = atomicAdd(&ccnt[w], 1);
              if (p < 32) swin[w][p] = v;
            }
          }
          int m = ccnt[w];
          if (m > 32) m = 32;
          float myv = (l < m) ? swin[w][l] : INFINITY;
          int clt = 0, ceq = 0;
          for (int jj = 0; jj < m; ++jj) {
            float y = swin[w][jj];
            clt += (y < myv) ? 1 : 0;
            ceq += (y == myv) ? 1 : 0;
          }
          int rr = k_lo - rbase;
          if (l < m) {
            if (clt <= rr && rr < clt + ceq) svsel[w][0] = myv;
            if (clt <= rr + 1 && rr + 1 < clt + ceq) svsel[w][1] = myv;
          }
          v_lo = svsel[w][0];
          v_hi = svsel[w][1];
          if (l == 0) ccnt[w] = count;  // restore
        } else {
          int clt[SMAX], ceq[SMAX];
#pragma unroll
          for (int s = 0; s < SMAX; ++s) { clt[s] = 0; ceq[s] = 0; }
          for (int jj = 0; jj < count; ++jj) {
            float y = cv[w][jj];
#pragma unroll
            for (int s = 0; s < SMAX; ++s) {
              clt[s] += (y < xv[s]) ? 1 : 0;
              ceq[s] += (y == xv[s]) ? 1 : 0;
            }
          }
#pragma unroll
          for (int s = 0; s < SMAX; ++s) {
            int slot = l + 64 * s;
            if (slot < count) {
              if (clt[s] <= k_lo && k_lo < clt[s] + ceq[s]) svsel[w][0] = xv[s];
              if (clt[s] <= k_lo + 1 && k_lo + 1 < clt[s] + ceq[s]) svsel[w][1] = xv[s];
            }
          }
          v_lo = svsel[w][0];
          v_hi = svsel[w][1];
        }
      }
      // guard: every non-candidate (>= wtop) must be excluded by thr
      float vlos0 = __fmul_rn(v_lo, scale);
      float vhis0 = __fmul_rn(v_hi, scale);
      float thr0 = __fadd_rn(__fmul_rn(vlos0, lw), __fmul_rn(vhis0, hw));
      if (__fmul_rn(wtop, scale) <= thr0) {
        wtop = fminf(rmin + (wtop - rmin) * 3.0f, rtop);
        attempt++; have = false; continue;
      }
      break;
    }

    float vlos = __fmul_rn(v_lo, scale);
    float vhis = __fmul_rn(v_hi, scale);
    float thr = __fadd_rn(__fmul_rn(vlos, lw), __fmul_rn(vhis, hw));
    float rmins = __fmul_rn(rmin, scale);

    int oi[SMAX]; int kp[SMAX];
#pragma unroll
    for (int s = 0; s < SMAX; ++s) {
      int slot = l + 64 * s;
      oi[s] = 0; kp[s] = 0;
      if (slot < count) {
        oi[s] = ci[w][slot];
        kp[s] = (__fmul_rn(xv[s], scale) <= thr) ? 1 : 0;
      }
    }
    int base = 0;
    float lsum = 0.0f;
    unsigned long long mlt = (l == 0) ? 0ull : (~0ull >> (64 - l));
#pragma unroll
    for (int s = 0; s < SMAX; ++s) {
      unsigned long long bal = __ballot(kp[s] != 0);
      int pos = base + (int)__popcll(bal & mlt);
      if (kp[s]) {
        float e0 = expf(__fsub_rn(rmins, __fmul_rn(xv[s], scale)));
        cv[w][pos] = e0;
        ci[w][pos] = oi[s];
        lsum += e0;
      }
      base += (int)__popcll(bal);
    }
    K = base;
#pragma unroll
    for (int off = 32; off > 0; off >>= 1) lsum += __shfl_xor(lsum, off);
    inv_total = 1.0f / lsum;
  } else {
    K = 0;
    inv_total = 1.0f / (float)Nk;
  }

  // ---- PV: lane = (batch b, col pair); one float2 load per element ----
  int b = l >> 4, c4 = (l & 15) * 2;
  int hcol = h * 32 + c4;
  const float* Vb = V + (size_t)b * Nk * 256;
  float acc0 = 0.0f, acc1 = 0.0f;
  if (K > 0) {
    for (int e = 0; e < K; ++e) {
      float we = cv[w][e];
      int n = ci[w][e];
      const float2 vv = *(const float2*)(Vb + (size_t)n * 256 + hcol);
      acc0 = fmaf(we, vv.x, acc0);
      acc1 = fmaf(we, vv.y, acc1);
    }
  } else {
    for (int n = 0; n < Nk; ++n) {
      const float2 vv = *(const float2*)(Vb + (size_t)n * 256 + hcol);
      acc0 += vv.x;
      acc1 += vv.y;
    }
  }
  size_t oidx = ((size_t)b * Nq + j) * 256 + hcol;
  store_bf(out_hi, out_lo, oidx, gelu_f(acc0 * inv_total));
  store_bf(out_hi, out_lo, oidx + 1, gelu_f(acc1 * inv_total));
}

// ---------------- final 256->1 projection -----------------------------------
__global__ __launch_bounds__(256) void k_de2(const float* __restrict__ A,
                                             const float* __restrict__ w,
                                             const float* __restrict__ b,
                                             float* __restrict__ out) {
  int t = threadIdx.x;
  int row = blockIdx.x * 4 + (t >> 6);
  int lane = t & 63;
  const float* ar = A + (size_t)row * 256;
  float s = 0.0f;
  for (int i = lane; i < 256; i += 64) s = fmaf(ar[i], w[i], s);
#pragma unroll
  for (int off = 32; off > 0; off >>= 1) s += __shfl_down(s, off);
  if (lane == 0) out[row] = s + b[0];
}

// ---------------------------------------------------------------------------
struct SelParams { int k_lo; float hw, lw, frac; };
static SelParams sel_params(double q, int N) {
  SelParams p;
  float idx_q = (float)(q / 100.0);
  float pos = idx_q * (float)(N - 1);
  float lo = floorf(pos);
  p.k_lo = (int)lo;
  p.hw = pos - lo;
  p.lw = 1.0f - p.hw;
  float need = (float)(p.k_lo + 2);
  p.frac = (need + 6.0f * sqrtf(need) + 8.0f) / (float)N;
  return p;
}

extern "C" void kernel_launch(void* const* d_in, const int* in_sizes, int n_in,
                              void* d_out, int out_size, void* d_ws, size_t ws_size,
                              hipStream_t stream) {
  const float* x      = (const float*)d_in[0];
  const float* mdd    = (const float*)d_in[1];
  const float* mdb    = (const float*)d_in[2];
  const float* mdu    = (const float*)d_in[3];
  const float* en_w   = (const float*)d_in[4];
  const float* en_b   = (const float*)d_in[5];
  const float* down_r = (const float*)d_in[6];
  const float* down_w = (const float*)d_in[7];
  const float* pa_r   = (const float*)d_in[8];
  const float* pa_w   = (const float*)d_in[9];
  const float* mlp1_w = (const float*)d_in[10];
  const float* mlp1_b = (const float*)d_in[11];
  const float* mlp2_w = (const float*)d_in[12];
  const float* mlp2_b = (const float*)d_in[13];
  const float* res_w  = (const float*)d_in[14];
  const float* res_b  = (const float*)d_in[15];
  const float* up_r   = (const float*)d_in[16];
  const float* up_w   = (const float*)d_in[17];
  const float* de1_w  = (const float*)d_in[18];
  const float* de1_b  = (const float*)d_in[19];
  const float* de2_w  = (const float*)d_in[20];
  const float* de2_b  = (const float*)d_in[21];
  float* out = (float*)d_out;
  char* base = (char*)d_ws;

  float* val               = (float*)base;                        // 16.78 MB (also de1 out)
  unsigned short* hB_hi    = (unsigned short*)(base + 16777216);  // 2.10 MB
  unsigned short* hB_lo    = (unsigned short*)(base + 18874368);  // 2.10 MB
  unsigned short* hfull_hi = (unsigned short*)(base + 20971520);  // 8.39 MB
  unsigned short* hfull_lo = (unsigned short*)(base + 29360128);
  unsigned short* paout_hi = (unsigned short*)(base + 37748736);
  unsigned short* paout_lo = (unsigned short*)(base + 46137344);
  unsigned short* hA_hi    = (unsigned short*)(base + 54525952);  // 2.10 MB
  unsigned short* hA_lo    = (unsigned short*)(base + 56623104);
  unsigned short* t1_hi    = (unsigned short*)(base + 58720256);
  unsigned short* t1_lo    = (unsigned short*)(base + 60817408);
  unsigned short* wrm_hi   = (unsigned short*)(base + 62914560);  // 1.70 MB
  unsigned short* wrm_lo   = (unsigned short*)(base + 64618496);
  unsigned short* wval_hi  = (unsigned short*)(base + 66322432);  // 0.79 MB
  unsigned short* wval_lo  = (unsigned short*)(base + 67108864);
  float* scales            = (float*)(base + 67895296);

  PrepArgs pa;
  pa.mlp1 = mlp1_w; pa.mlp2 = mlp2_w; pa.res = res_w; pa.de1 = de1_w;
  pa.down = down_w; pa.pa = pa_w; pa.up = up_w;
  pa.down_r = down_r; pa.pa_r = pa_r; pa.up_r = up_r;
  pa.x = x; pa.en_w = en_w; pa.en_b = en_b;
  pa.rm_hi = wrm_hi; pa.rm_lo = wrm_lo; pa.val_hi = wval_hi; pa.val_lo = wval_lo;
  pa.hfull_hi = hfull_hi; pa.hfull_lo = hfull_lo;
  pa.scales = scales;
  // weights/scales prep (4865 blocks) + encoder lift (16384 blocks) fused
  k_prep<<<21249, 256, 0, stream>>>(pa);

  // down stage (H=8, Nq=1024, Nk=4096, q=3 -> keep ~124)
  SelParams pd = sel_params(3.0, 4096);
  k_gemm<0, 0, 0><<<dim3(256, 4), 256, 0, stream>>>(
      hfull_hi, hfull_lo, wval_hi, wval_lo, nullptr, nullptr, val, nullptr, nullptr);
  k_wselpv<4096, 256, 4><<<2048, 256, 0, stream>>>(
      mdd, scales, 0, 1024, pd.k_lo, pd.hw, pd.lw, pd.frac, val, 4096, hA_hi, hA_lo);

  // processor blocks (Nq=Nk=1024, q=5 -> keep ~53); hlat ping-pongs A<->B
  SelParams pb = sel_params(5.0, 1024);
  for (int i = 0; i < 4; i++) {
    unsigned short* in_hi  = (i & 1) ? hB_hi : hA_hi;
    unsigned short* in_lo  = (i & 1) ? hB_lo : hA_lo;
    unsigned short* out_hi = (i & 1) ? hA_hi : hB_hi;
    unsigned short* out_lo = (i & 1) ? hA_lo : hB_lo;
    k_gemm<0, 0, 0><<<dim3(64, 4), 256, 0, stream>>>(
        in_hi, in_lo, wval_hi + 65536 + i * 65536, wval_lo + 65536 + i * 65536,
        nullptr, nullptr, val, nullptr, nullptr);
    k_wselpv<1024, 256, 8><<<2048, 256, 0, stream>>>(
        mdb + (size_t)i * 8388608, scales, 8 + i * 8, 1024, pb.k_lo, pb.hw, pb.lw,
        pb.frac, val, 1024, paout_hi, paout_lo);
    k_gemm<1, 0, 1><<<dim3(64, 4), 256, 0, stream>>>(
        paout_hi, paout_lo, wrm_hi + i * 65536, wrm_lo + i * 65536,
        mlp1_b + i * 256, nullptr, nullptr, t1_hi, t1_lo);
    k_gemm2<<<dim3(64, 4), 256, 0, stream>>>(
        t1_hi, t1_lo, wrm_hi + 262144 + i * 65536, wrm_lo + 262144 + i * 65536,
        in_hi, in_lo, wrm_hi + 524288 + i * 65536, wrm_lo + 524288 + i * 65536,
        mlp2_b + i * 256, res_b + i * 256, out_hi, out_lo);
  }
  // after 4 iterations the live hlat is back in hA

  // up stage (H=8, Nq=4096, Nk=1024, q=3 -> keep ~32)
  SelParams pu = sel_params(3.0, 1024);
  k_gemm<0, 0, 0><<<dim3(64, 4), 256, 0, stream>>>(
      hA_hi, hA_lo, wval_hi + 327680, wval_lo + 327680, nullptr, nullptr,
      val, nullptr, nullptr);
  k_wselpv<1024, 192, 8><<<8192, 256, 0, stream>>>(
      mdu, scales, 40, 4096, pu.k_lo, pu.hw, pu.lw, pu.frac, val, 1024,
      paout_hi, paout_lo);

  // decoder
  k_gemm<1, 0, 0><<<dim3(256, 4), 256, 0, stream>>>(
      paout_hi, paout_lo, wrm_hi + 786432, wrm_lo + 786432, de1_b, nullptr,
      val, nullptr, nullptr);
  k_de2<<<4096, 256, 0, stream>>>(val, de2_w, de2_b, out);
}